// Round 4
// baseline (354.899 us; speedup 1.0000x reference)
//
#include <hip/hip_runtime.h>

#define B_   4
#define C_   256
#define O_   128
#define N_   4096
#define QKVW 384

typedef __attribute__((ext_vector_type(8))) _Float16 f16x8;
typedef __attribute__((ext_vector_type(4))) float    f32x4;

struct __align__(8) us4 { unsigned short x, y, z, w; };

__device__ __forceinline__ float bf2f(unsigned short u) {
    unsigned v = ((unsigned)u) << 16;
    union { unsigned u; float f; } c; c.u = v; return c.f;
}
__device__ __forceinline__ unsigned short f2bf(float f) {
    union { float f; unsigned u; } c; c.f = f;
    unsigned r = c.u + 0x7fffu + ((c.u >> 16) & 1u);
    return (unsigned short)(r >> 16);
}
__device__ __forceinline__ unsigned short f2h(float f) {
    _Float16 h = (_Float16)f;
    union { _Float16 h; unsigned short s; } c; c.h = h; return c.s;
}

// dtype-agnostic loads: isf32 selects float32 vs bf16 interpretation of base.
__device__ __forceinline__ void load4f(const void* base, size_t idx, int isf32, float o[4]) {
    if (isf32) {
        float4 v = *(const float4*)((const float*)base + idx);
        o[0] = v.x; o[1] = v.y; o[2] = v.z; o[3] = v.w;
    } else {
        us4 v = *(const us4*)((const unsigned short*)base + idx);
        o[0] = bf2f(v.x); o[1] = bf2f(v.y); o[2] = bf2f(v.z); o[3] = bf2f(v.w);
    }
}
__device__ __forceinline__ float load1f(const void* base, size_t idx, int isf32) {
    return isf32 ? ((const float*)base)[idx] : bf2f(((const unsigned short*)base)[idx]);
}

// ---------------------------------------------------------------------------
// Kernel 0: input dtype detector. If x is fp32, even u16s are float low-
// mantissa halves -> ~uniform bits -> ~80% absurd bf16 exponents. If x is
// genuine bf16 N(0,1), ~0%. Reads only first 16 KB (safe either way).
// Output dtype follows input dtype (harness rule: buffers match the
// reference dtypes, and the reference is uniform-precision).
// ---------------------------------------------------------------------------
__global__ __launch_bounds__(256) void detect_kernel(
    const unsigned short* __restrict__ xu, int* __restrict__ flag)
{
    __shared__ int cnt;
    if (threadIdx.x == 0) cnt = 0;
    __syncthreads();
    int local = 0;
    for (int i = threadIdx.x; i < 4096; i += 256) {
        unsigned short u = xu[2 * i];        // even positions
        int e = (u >> 7) & 0xFF;
        if (e == 0xFF || e >= 0x90 || (e > 0 && e <= 0x60)) local++;
    }
    atomicAdd(&cnt, local);
    __syncthreads();
    if (threadIdx.x == 0) *flag = (cnt > 1024) ? 1 : 0;
}

// ---------------------------------------------------------------------------
// Kernel 1: qkv[b][n][jsel*128 + j] = sum_c x[b][c][n] * w[j][c] + bias[j]
// grid (N/64, 3, B), block 256 (4 waves), tile 64n x 128j, BK=64.
// ---------------------------------------------------------------------------
__global__ __launch_bounds__(256) void qkv_kernel(
    const void* __restrict__ x,    // [B][C][N] fp32 or bf16
    const void* __restrict__ wt,   // [128][256]
    const void* __restrict__ wp,
    const void* __restrict__ wg,
    const void* __restrict__ bt,   // [128]
    const void* __restrict__ bp,
    const void* __restrict__ bg,
    const int*  __restrict__ flag,
    unsigned short* __restrict__ qkv)  // fp16 [B][N][384]
{
    const int isf32 = *flag;
    const int jsel = blockIdx.y;
    const void* w  = jsel == 0 ? wt : (jsel == 1 ? wp : wg);
    const void* bi = jsel == 0 ? bt : (jsel == 1 ? bp : bg);
    const int b  = blockIdx.z;
    const int n0 = blockIdx.x * 64;
    const int tid  = threadIdx.x;
    const int wv   = tid >> 6, lane = tid & 63;
    const int quad = lane >> 4, l16 = lane & 15;

    __shared__ alignas(16) unsigned short As[64][72];   // [n][c] fp16 (transposed x)
    __shared__ alignas(16) unsigned short Bs[128][72];  // [j][c] fp16

    f32x4 acc[8];
    for (int i = 0; i < 8; i++) acc[i] = (f32x4)0.f;

    for (int kc = 0; kc < C_; kc += 64) {
        __syncthreads();
        // stage A: x[b][kc+c][n0+n] -> As[n][c] fp16, transpose via VGPR
        for (int it = 0; it < 4; it++) {
            int l = it * 256 + tid;          // [0,1024)
            int c = l >> 4;                  // [0,64)
            int ng = l & 15;                 // n = ng*4
            float v[4];
            load4f(x, (size_t)(b * C_ + kc + c) * N_ + n0 + ng * 4, isf32, v);
            As[ng * 4 + 0][c] = f2h(v[0]);
            As[ng * 4 + 1][c] = f2h(v[1]);
            As[ng * 4 + 2][c] = f2h(v[2]);
            As[ng * 4 + 3][c] = f2h(v[3]);
        }
        // stage B: w[j][kc+c] -> Bs[j][c] fp16
        for (int it = 0; it < 8; it++) {
            int l = it * 256 + tid;          // [0,2048)
            int j = l >> 4;                  // [0,128)
            int cg = l & 15;                 // c = cg*4
            float v[4];
            load4f(w, (size_t)j * C_ + kc + cg * 4, isf32, v);
            Bs[j][cg * 4 + 0] = f2h(v[0]);
            Bs[j][cg * 4 + 1] = f2h(v[1]);
            Bs[j][cg * 4 + 2] = f2h(v[2]);
            Bs[j][cg * 4 + 3] = f2h(v[3]);
        }
        __syncthreads();
        for (int s = 0; s < 2; s++) {
            f16x8 a = *(const f16x8*)&As[wv * 16 + l16][s * 32 + quad * 8];
            for (int jt = 0; jt < 8; jt++) {
                f16x8 bb = *(const f16x8*)&Bs[jt * 16 + l16][s * 32 + quad * 8];
                acc[jt] = __builtin_amdgcn_mfma_f32_16x16x32_f16(a, bb, acc[jt], 0, 0, 0);
            }
        }
    }
    // epilogue: D col = lane&15 (j), row = quad*4+reg (n)
    for (int jt = 0; jt < 8; jt++) {
        int j = jt * 16 + l16;
        float bias = load1f(bi, j, isf32);
        for (int r = 0; r < 4; r++) {
            int n = n0 + wv * 16 + quad * 4 + r;
            qkv[(size_t)(b * N_ + n) * QKVW + jsel * O_ + j] = f2h(acc[jt][r] + bias);
        }
    }
}

// ---------------------------------------------------------------------------
// Kernel 2: flash attention. grid (N/64, B), block 256 (4 waves, 16 q-rows
// each). TK=64 key tile. Q frags in registers; K staged [m][o]; G staged
// transposed [o][m]; P round-trips LDS (C-layout -> A-layout).
// ---------------------------------------------------------------------------
__global__ __launch_bounds__(256) void attn_kernel(
    const unsigned short* __restrict__ qkv,  // fp16 [B][N][384]
    unsigned short* __restrict__ y)          // fp16 [B][N][128]
{
    const int b  = blockIdx.y;
    const int n0 = blockIdx.x * 64;
    const int tid  = threadIdx.x;
    const int wv   = tid >> 6, lane = tid & 63;
    const int quad = lane >> 4, l16 = lane & 15;

    __shared__ alignas(16) unsigned short Ks[64][136];   // [key][o]
    __shared__ alignas(16) unsigned short Gs[128][72];   // [o][key] (transposed)
    __shared__ alignas(16) unsigned short Ps[4][16][72]; // per-wave P tile

    // Q fragments: A[m=q(lane&15)][k=o(s*32+quad*8+i)]
    f16x8 qf[4];
    {
        int qrow = n0 + wv * 16 + l16;
        const unsigned short* qp = qkv + (size_t)(b * N_ + qrow) * QKVW;
        for (int s = 0; s < 4; s++)
            qf[s] = *(const f16x8*)(qp + s * 32 + quad * 8);
    }

    f32x4 oacc[8];
    for (int i = 0; i < 8; i++) oacc[i] = (f32x4)0.f;
    float mstate[4], lstate[4];
    for (int r = 0; r < 4; r++) { mstate[r] = -INFINITY; lstate[r] = 0.f; }

    for (int mt = 0; mt < N_ / 64; mt++) {
        int m0 = mt * 64;
        __syncthreads();
        // stage K rows: qkv[b][m0+mm][128+o] -> Ks[mm][o]
        for (int it = 0; it < 8; it++) {
            int l = it * 256 + tid;  // [0,2048)
            int mm = l >> 5;         // [0,64)
            int og = l & 31;         // o = og*4
            us4 v = *(const us4*)(qkv + (size_t)(b * N_ + m0 + mm) * QKVW + O_ + og * 4);
            *(us4*)&Ks[mm][og * 4] = v;
        }
        // stage G transposed: qkv[b][m0+mm][256+o] -> Gs[o][mm]
        for (int it = 0; it < 8; it++) {
            int l = it * 256 + tid;
            int mm = l >> 5;
            int og = l & 31;
            us4 v = *(const us4*)(qkv + (size_t)(b * N_ + m0 + mm) * QKVW + 2 * O_ + og * 4);
            Gs[og * 4 + 0][mm] = v.x;
            Gs[og * 4 + 1][mm] = v.y;
            Gs[og * 4 + 2][mm] = v.z;
            Gs[og * 4 + 3][mm] = v.w;
        }
        __syncthreads();

        // S = Q K^T : 4 key subtiles x 4 k-steps
        f32x4 sacc[4];
        for (int kt = 0; kt < 4; kt++) sacc[kt] = (f32x4)0.f;
        for (int s = 0; s < 4; s++) {
            for (int kt = 0; kt < 4; kt++) {
                f16x8 kb = *(const f16x8*)&Ks[kt * 16 + l16][s * 32 + quad * 8];
                sacc[kt] = __builtin_amdgcn_mfma_f32_16x16x32_f16(qf[s], kb, sacc[kt], 0, 0, 0);
            }
        }

        // online softmax per owned row (row = quad*4 + r)
        for (int r = 0; r < 4; r++) {
            float rm = fmaxf(fmaxf(sacc[0][r], sacc[1][r]), fmaxf(sacc[2][r], sacc[3][r]));
            for (int off = 1; off < 16; off <<= 1)
                rm = fmaxf(rm, __shfl_xor(rm, off));
            float mnew  = fmaxf(mstate[r], rm);
            float alpha = __expf(mstate[r] - mnew);
            float p0 = __expf(sacc[0][r] - mnew);
            float p1 = __expf(sacc[1][r] - mnew);
            float p2 = __expf(sacc[2][r] - mnew);
            float p3 = __expf(sacc[3][r] - mnew);
            float rs = p0 + p1 + p2 + p3;
            for (int off = 1; off < 16; off <<= 1)
                rs += __shfl_xor(rs, off);
            lstate[r] = lstate[r] * alpha + rs;
            mstate[r] = mnew;
            for (int jt = 0; jt < 8; jt++) oacc[jt][r] *= alpha;
            int row = quad * 4 + r;
            Ps[wv][row][ 0 + l16] = f2h(p0);
            Ps[wv][row][16 + l16] = f2h(p1);
            Ps[wv][row][32 + l16] = f2h(p2);
            Ps[wv][row][48 + l16] = f2h(p3);
        }
        __syncthreads();   // P visibility (and keeps barrier counts uniform)

        // O += P G : A from Ps (q=lane&15, k=key), B from Gs (o2=lane&15, k=key)
        for (int s = 0; s < 2; s++) {
            f16x8 pa = *(const f16x8*)&Ps[wv][l16][s * 32 + quad * 8];
            for (int jt = 0; jt < 8; jt++) {
                f16x8 gb = *(const f16x8*)&Gs[jt * 16 + l16][s * 32 + quad * 8];
                oacc[jt] = __builtin_amdgcn_mfma_f32_16x16x32_f16(pa, gb, oacc[jt], 0, 0, 0);
            }
        }
    }

    // epilogue: y[b][n][o] = O / l
    for (int r = 0; r < 4; r++) {
        float inv = 1.0f / lstate[r];
        int n = n0 + wv * 16 + quad * 4 + r;
        unsigned short* yp = y + (size_t)(b * N_ + n) * O_;
        for (int jt = 0; jt < 8; jt++)
            yp[jt * 16 + l16] = f2h(oacc[jt][r] * inv);
    }
}

// ---------------------------------------------------------------------------
// Kernel 3: z[b][c][n] = sum_o wW[c][o] y[b][n][o] + bW[c] + x[b][c][n]
// grid (N/128, C/64, B), block 256. Output dtype follows input dtype (flag).
// ---------------------------------------------------------------------------
__global__ __launch_bounds__(256) void out_kernel(
    const unsigned short* __restrict__ y,    // fp16 [B][N][128]
    const void* __restrict__ wW,             // [256][128] fp32 or bf16
    const void* __restrict__ bW,             // [256]
    const void* __restrict__ x,              // [B][C][N]
    const int*  __restrict__ flag,
    void* __restrict__ z)                    // fp32 or bf16 out
{
    const int isf32 = *flag;
    const int b  = blockIdx.z;
    const int c0 = blockIdx.y * 64;
    const int n0 = blockIdx.x * 128;
    const int tid  = threadIdx.x;
    const int wv   = tid >> 6, lane = tid & 63;
    const int quad = lane >> 4, l16 = lane & 15;

    __shared__ alignas(16) unsigned short Ys[128][136];  // [n][o] fp16
    __shared__ alignas(16) unsigned short Ws[64][136];   // [c][o] fp16

    for (int it = 0; it < 16; it++) {
        int l = it * 256 + tid;   // [0,4096)
        int nn = l >> 5;
        int og = l & 31;
        us4 v = *(const us4*)(y + (size_t)(b * N_ + n0 + nn) * O_ + og * 4);
        *(us4*)&Ys[nn][og * 4] = v;
    }
    for (int it = 0; it < 8; it++) {
        int l = it * 256 + tid;   // [0,2048)
        int cc = l >> 5;
        int og = l & 31;
        float v[4];
        load4f(wW, (size_t)(c0 + cc) * O_ + og * 4, isf32, v);
        Ws[cc][og * 4 + 0] = f2h(v[0]);
        Ws[cc][og * 4 + 1] = f2h(v[1]);
        Ws[cc][og * 4 + 2] = f2h(v[2]);
        Ws[cc][og * 4 + 3] = f2h(v[3]);
    }
    __syncthreads();

    f32x4 acc[8];
    for (int i = 0; i < 8; i++) acc[i] = (f32x4)0.f;
    for (int s = 0; s < 4; s++) {
        f16x8 a = *(const f16x8*)&Ws[wv * 16 + l16][s * 32 + quad * 8];
        for (int nt = 0; nt < 8; nt++) {
            f16x8 bb = *(const f16x8*)&Ys[nt * 16 + l16][s * 32 + quad * 8];
            acc[nt] = __builtin_amdgcn_mfma_f32_16x16x32_f16(a, bb, acc[nt], 0, 0, 0);
        }
    }
    for (int r = 0; r < 4; r++) {
        int c = c0 + wv * 16 + quad * 4 + r;
        float bias = load1f(bW, c, isf32);
        for (int nt = 0; nt < 8; nt++) {
            int n = n0 + nt * 16 + l16;
            size_t idx = (size_t)(b * C_ + c) * N_ + n;
            float zv = acc[nt][r] + bias + load1f(x, idx, isf32);
            if (isf32) ((float*)z)[idx] = zv;
            else       ((unsigned short*)z)[idx] = f2bf(zv);
        }
    }
}

// ---------------------------------------------------------------------------
extern "C" void kernel_launch(void* const* d_in, const int* in_sizes, int n_in,
                              void* d_out, int out_size, void* d_ws, size_t ws_size,
                              hipStream_t stream) {
    const void* x  = d_in[0];
    const void* wt = d_in[1];
    const void* bt = d_in[2];
    const void* wp = d_in[3];
    const void* bp = d_in[4];
    const void* wg = d_in[5];
    const void* bg = d_in[6];
    const void* wW = d_in[7];
    const void* bW = d_in[8];

    // workspace layout: fp16 qkv + fp16 y + dtype flag
    unsigned short* qkv  = (unsigned short*)d_ws;          // [4][4096][384] = 12.58 MB
    unsigned short* y    = qkv + (size_t)B_ * N_ * QKVW;   // [4][4096][128] =  4.19 MB
    int*            flag = (int*)(y + (size_t)B_ * N_ * O_);

    detect_kernel<<<1, 256, 0, stream>>>((const unsigned short*)x, flag);

    dim3 g1(N_ / 64, 3, B_);
    qkv_kernel<<<g1, 256, 0, stream>>>(x, wt, wp, wg, bt, bp, bg, flag, qkv);

    dim3 g2(N_ / 64, B_);
    attn_kernel<<<g2, 256, 0, stream>>>(qkv, y);

    dim3 g3(N_ / 128, C_ / 64, B_);
    out_kernel<<<g3, 256, 0, stream>>>(y, wW, bW, x, flag, d_out);
}